// Round 1
// baseline (367.034 us; speedup 1.0000x reference)
//
#include <hip/hip_runtime.h>
#include <math.h>

namespace {

constexpr int MAXM = 132;  // padded max bin count (final M = 129)
constexpr int RPB  = 4;    // rays per block (one ray per 64-lane wave)

__device__ __forceinline__ float scan_add(float v, int lane) {
#pragma unroll
  for (int off = 1; off < 64; off <<= 1) {
    float up = __shfl_up(v, off, 64);
    if (lane >= off) v += up;
  }
  return v;
}

__device__ __forceinline__ float scan_mul(float v, int lane) {
#pragma unroll
  for (int off = 1; off < 64; off <<= 1) {
    float up = __shfl_up(v, off, 64);
    if (lane >= off) v *= up;
  }
  return v;
}

__device__ __forceinline__ float reduce_add(float v) {
#pragma unroll
  for (int off = 32; off >= 1; off >>= 1) v += __shfl_xor(v, off, 64);
  return v;
}

__global__ __launch_bounds__(RPB * 64) void neus_sampler(
    const float* __restrict__ org, const float* __restrict__ dirp,
    const float* __restrict__ nearp, const float* __restrict__ farp,
    float* __restrict__ out, int R) {
  __shared__ float sbA[RPB][MAXM], sdA[RPB][MAXM];
  __shared__ float sbB[RPB][MAXM], sdB[RPB][MAXM];
  __shared__ float cdfS[RPB][MAXM];
  __shared__ float nbS[RPB][20];

  const int wave = threadIdx.x >> 6;
  const int lane = threadIdx.x & 63;
  int ray = blockIdx.x * RPB + wave;
  const bool live = ray < R;
  if (ray >= R) ray = R - 1;  // clamp: dead waves duplicate work, skip store

  const float ox = org[3 * ray + 0], oy = org[3 * ray + 1], oz = org[3 * ray + 2];
  const float dx = dirp[3 * ray + 0], dy = dirp[3 * ray + 1], dz = dirp[3 * ray + 2];
  const float nr = nearp[ray], fr = farp[ray];
  const float fmn = fr - nr;

  float* sb  = sbA[wave];
  float* sd  = sdA[wave];
  float* sb2 = sbB[wave];
  float* sd2 = sdB[wave];
  float* cd  = cdfS[wave];
  float* nb  = nbS[wave];

  // ---- init: sbins = linspace(0,1,65); sdf at the 64 starts ----
  for (int i = lane; i < 65; i += 64) sb[i] = (float)i * (1.0f / 64.0f);
  {
    float s = (float)lane * (1.0f / 64.0f);
    float e = nr + s * fmn;
    float px = ox + dx * e, py = oy + dy * e, pz = oz + dz * e;
    sd[lane] = sqrtf(px * px + py * py + pz * pz) - 1.0f;
  }
  __syncthreads();

  int M = 65;
#pragma unroll 1
  for (int it = 0; it < 4; ++it) {
    const float inv_s = 64.0f * (float)(1 << it);

    // ---- phase A: alphas, transmittance (cumprod scan), weights ----
    float wreg[2];
    float wsum_part = 0.0f;
    {
      float carryT = 1.0f;
#pragma unroll
      for (int c = 0; c < 2; ++c) {
        int i = lane + (c << 6);
        float alpha = 0.0f, q = 1.0f;
        if (i <= M - 3) {
          float s0v = sb[i], s1v = sb[i + 1];
          float e0 = nr + s0v * fmn, e1 = nr + s1v * fmn;
          float delta = e1 - e0;
          float sd0 = sd[i], sd1 = sd[i + 1];
          float cosv = (sd1 - sd0) / (delta + 1e-5f);
          float cosp = 0.0f;
          if (i > 0) {
            float em1 = nr + sb[i - 1] * fmn;
            cosp = (sd0 - sd[i - 1]) / ((e0 - em1) + 1e-5f);
          }
          float cv = fminf(cosp, cosv);
          cv = fminf(fmaxf(cv, -1000.0f), 0.0f);
          float mid = 0.5f * (sd0 + sd1);
          float pe = mid - cv * delta * 0.5f;
          float ne = mid + cv * delta * 0.5f;
          float pc = 1.0f / (1.0f + __expf(-pe * inv_s));
          float nc = 1.0f / (1.0f + __expf(-ne * inv_s));
          alpha = (pc - nc + 1e-5f) / (pc + 1e-5f);
          q = 1.0f - alpha + 1e-7f;
        }
        float S = scan_mul(q, lane);
        float ex = __shfl_up(S, 1, 64);
        if (lane == 0) ex = 1.0f;
        float T = carryT * ex;           // exclusive cumprod = transmittance
        carryT *= __shfl(S, 63, 64);
        float wv = (i <= M - 2) ? alpha * T : 0.0f;  // i==M-2: alpha=0 -> appended zero weight
        wreg[c] = wv;
        wsum_part += wv;
      }
    }
    float wsum = reduce_add(wsum_part);
    float pad = fmaxf(1e-5f - wsum, 0.0f);
    float wadd = pad / (float)(M - 1);
    float wst = wsum + pad;

    // ---- phase A2: cdf (cumsum scan), store to LDS ----
    {
      float carryS = 0.0f;
#pragma unroll
      for (int c = 0; c < 2; ++c) {
        int i = lane + (c << 6);
        float pv = (i <= M - 2) ? (wreg[c] + wadd) / wst : 0.0f;
        float S = scan_add(pv, lane);
        float cum = carryS + S;
        carryS += __shfl(S, 63, 64);
        if (i <= M - 2) cd[i + 1] = fminf(1.0f, cum);
      }
      if (lane == 0) cd[0] = 0.0f;
    }
    __syncthreads();

    // ---- phase B: 17 inverse-CDF samples (lanes 0..16) ----
    if (lane < 17) {
      float u = (float)((double)lane * ((1.0 - 1.0 / 17.0) / 16.0));
      u += (float)(1.0 / 34.0);
      int lo = 0, hi = M;  // searchsorted right on cd[0..M-1]
      while (lo < hi) {
        int md = (lo + hi) >> 1;
        if (cd[md] <= u) lo = md + 1; else hi = md;
      }
      int below = lo - 1;
      if (below < 0) below = 0;
      if (below > M - 1) below = M - 1;
      int above = lo;
      if (above > M - 1) above = M - 1;
      float c0 = cd[below], c1 = cd[above];
      float b0 = sb[below], b1 = sb[above];
      float den = c1 - c0;
      den = (den < 1e-5f) ? 1.0f : den;
      float t = (u - c0) / den;
      t = fminf(fmaxf(t, 0.0f), 1.0f);
      nb[lane] = b0 + t * (b1 - b0);
    }
    __syncthreads();

    // ---- phase C: stable merge of sorted starts (old first on ties) ----
#pragma unroll
    for (int c = 0; c < 2; ++c) {
      int i = lane + (c << 6);
      if (i <= M - 2) {
        float a = sb[i];
        int cnt = 0;  // count of new bins strictly less than a
#pragma unroll
        for (int j = 0; j < 16; ++j) cnt += (nb[j] < a) ? 1 : 0;
        int pos = i + cnt;
        sb2[pos] = a;
        sd2[pos] = sd[i];
      }
    }
    if (lane < 16) {
      float b = nb[lane];
      int lo = 0, hi = M - 1;  // upper_bound over old starts sb[0..M-2]
      while (lo < hi) {
        int md = (lo + hi) >> 1;
        if (sb[md] <= b) lo = md + 1; else hi = md;
      }
      int pos = lane + lo;
      sb2[pos] = b;
      float e = nr + b * fmn;  // sdf at the new start (same value the ref computes next iter)
      float px = ox + dx * e, py = oy + dy * e, pz = oz + dz * e;
      sd2[pos] = sqrtf(px * px + py * py + pz * pz) - 1.0f;
    }
    if (lane == 0) sb2[M + 15] = fmaxf(sb[M - 1], nb[16]);
    __syncthreads();
    {
      float* t = sb; sb = sb2; sb2 = t;
      t = sd; sd = sd2; sd2 = t;
    }
    M += 16;
  }

  // ---- final: out[ray, i, :] = origin + dir * (near + sb[i]*(far-near)), i<128 ----
  if (live) {
#pragma unroll
    for (int c = 0; c < 2; ++c) {
      int i = lane + (c << 6);
      float e = nr + sb[i] * fmn;
      float* o = out + ((size_t)ray * 128 + (size_t)i) * 3;
      o[0] = ox + dx * e;
      o[1] = oy + dy * e;
      o[2] = oz + dz * e;
    }
  }
}

}  // namespace

extern "C" void kernel_launch(void* const* d_in, const int* in_sizes, int n_in,
                              void* d_out, int out_size, void* d_ws, size_t ws_size,
                              hipStream_t stream) {
  const float* org  = (const float*)d_in[0];
  const float* dirp = (const float*)d_in[1];
  const float* nrp  = (const float*)d_in[2];
  const float* frp  = (const float*)d_in[3];
  float* out = (float*)d_out;
  const int R = in_sizes[0] / 3;
  const int grid = (R + RPB - 1) / RPB;
  hipLaunchKernelGGL(neus_sampler, dim3(grid), dim3(RPB * 64), 0, stream,
                     org, dirp, nrp, frp, out, R);
}

// Round 2
// 256.894 us; speedup vs baseline: 1.4287x; 1.4287x over previous
//
#include <hip/hip_runtime.h>
#include <math.h>

namespace {

constexpr int MAXM = 132;  // padded max bin count (final M = 129)
constexpr int RPB  = 4;    // rays per block (one ray per 64-lane wave)

// ---- DPP helpers (gfx9-family encodings, valid on CDNA4) ----
// ctrl: row_shr:N = 0x110+N, row_bcast15 = 0x142, row_bcast31 = 0x143,
//       wave_shr:1 = 0x138
template <int CTRL, int ROW_MASK>
__device__ __forceinline__ float dpp_f(float x, float oldv) {
  union { float f; int i; } a, b, r;
  a.f = x; b.f = oldv;
  r.i = __builtin_amdgcn_update_dpp(b.i, a.i, CTRL, ROW_MASK, 0xf, false);
  return r.f;
}

__device__ __forceinline__ float readlane_f(float x, int l) {
  union { float f; int i; } a, r;
  a.f = x;
  r.i = __builtin_amdgcn_readlane(a.i, l);
  return r.f;
}

// 64-lane inclusive scans, pure VALU (no DS ops)
__device__ __forceinline__ float scan_mul_dpp(float v) {
  v *= dpp_f<0x111, 0xf>(v, 1.0f);
  v *= dpp_f<0x112, 0xf>(v, 1.0f);
  v *= dpp_f<0x114, 0xf>(v, 1.0f);
  v *= dpp_f<0x118, 0xf>(v, 1.0f);
  v *= dpp_f<0x142, 0xa>(v, 1.0f);  // row_bcast:15 -> rows 1,3
  v *= dpp_f<0x143, 0xc>(v, 1.0f);  // row_bcast:31 -> rows 2,3
  return v;
}

__device__ __forceinline__ float scan_add_dpp(float v) {
  v += dpp_f<0x111, 0xf>(v, 0.0f);
  v += dpp_f<0x112, 0xf>(v, 0.0f);
  v += dpp_f<0x114, 0xf>(v, 0.0f);
  v += dpp_f<0x118, 0xf>(v, 0.0f);
  v += dpp_f<0x142, 0xa>(v, 0.0f);
  v += dpp_f<0x143, 0xc>(v, 0.0f);
  return v;
}

__device__ __forceinline__ float rcpf(float x) { return __builtin_amdgcn_rcpf(x); }

__device__ __forceinline__ void wbar() { __builtin_amdgcn_wave_barrier(); }

__global__ __launch_bounds__(RPB * 64, 8) void neus_sampler(
    const float* __restrict__ org, const float* __restrict__ dirp,
    const float* __restrict__ nearp, const float* __restrict__ farp,
    float* __restrict__ out, int R) {
  __shared__ float sbA[RPB][MAXM], sdA[RPB][MAXM];
  __shared__ float sbB[RPB][MAXM], sdB[RPB][MAXM];
  __shared__ float cdfS[RPB][MAXM];
  __shared__ __align__(16) float nbS[RPB][20];

  const int wave = threadIdx.x >> 6;
  const int lane = threadIdx.x & 63;
  int ray = blockIdx.x * RPB + wave;
  const bool live = ray < R;
  if (!live) ray = R - 1;

  const float ox = org[3 * ray + 0], oy = org[3 * ray + 1], oz = org[3 * ray + 2];
  const float dx = dirp[3 * ray + 0], dy = dirp[3 * ray + 1], dz = dirp[3 * ray + 2];
  const float nr = nearp[ray], fr = farp[ray];
  const float fmn = fr - nr;

  float* sb  = sbA[wave];
  float* sd  = sdA[wave];
  float* sb2 = sbB[wave];
  float* sd2 = sdB[wave];
  float* cd  = cdfS[wave];
  float* nb  = nbS[wave];

  // ---- init: sbins = linspace(0,1,65); sdf at the 64 starts ----
  for (int i = lane; i < 65; i += 64) sb[i] = (float)i * (1.0f / 64.0f);
  {
    float s = (float)lane * (1.0f / 64.0f);
    float e = nr + s * fmn;
    float px = ox + dx * e, py = oy + dy * e, pz = oz + dz * e;
    sd[lane] = sqrtf(px * px + py * py + pz * pz) - 1.0f;
  }
  wbar();

  int M = 65;
#pragma unroll 1
  for (int it = 0; it < 4; ++it) {
    const float inv_s = 64.0f * (float)(1 << it);
    const bool has1 = (M > 66);  // chunk 1 has live elements (it >= 1)

    // ---- phase A: alphas, transmittance (DPP cumprod), raw-weight cumsum ----
    float cum0 = 0.0f, cum1 = 0.0f, carryS = 0.0f;
    float carryT, cos_carry;
    {
      // chunk 0: i = lane
      int i = lane;
      bool act = (i <= M - 3);
      float s0v = sb[i], s1v = sb[i + 1];
      float sd0 = sd[i], sd1 = sd[i + 1];
      float delta = (s1v - s0v) * fmn;
      float cosv = (sd1 - sd0) * rcpf(delta + 1e-5f);
      cos_carry = readlane_f(cosv, 63);
      float cosp = dpp_f<0x138, 0xf>(cosv, 0.0f);  // wave_shr:1, lane0 -> 0
      float cv = fmaxf(fminf(fminf(cosp, cosv), 0.0f), -1000.0f);
      float mid = 0.5f * (sd0 + sd1);
      float hd = cv * delta * 0.5f;
      float pc = rcpf(1.0f + __expf(-(mid - hd) * inv_s));
      float nc = rcpf(1.0f + __expf(-(mid + hd) * inv_s));
      float a = (pc - nc + 1e-5f) * rcpf(pc + 1e-5f);
      float alpha = act ? a : 0.0f;
      float q = act ? (1.0f - alpha + 1e-7f) : 1.0f;
      float S = scan_mul_dpp(q);
      float T = dpp_f<0x138, 0xf>(S, 1.0f);  // exclusive cumprod
      carryT = readlane_f(S, 63);
      float wv = alpha * T;  // ==0 for i>=M-2 (alpha masked)
      float Sw = scan_add_dpp(wv);
      cum0 = Sw;
      carryS = readlane_f(Sw, 63);
    }
    if (has1) {
      // chunk 1: i = lane + 64
      int i = lane + 64;
      bool act = (i <= M - 3);
      float s0v = sb[i], s1v = sb[i + 1];
      float sd0 = sd[i], sd1 = sd[i + 1];
      float delta = (s1v - s0v) * fmn;
      float cosv = (sd1 - sd0) * rcpf(delta + 1e-5f);
      float cosp = dpp_f<0x138, 0xf>(cosv, cos_carry);
      float cv = fmaxf(fminf(fminf(cosp, cosv), 0.0f), -1000.0f);
      float mid = 0.5f * (sd0 + sd1);
      float hd = cv * delta * 0.5f;
      float pc = rcpf(1.0f + __expf(-(mid - hd) * inv_s));
      float nc = rcpf(1.0f + __expf(-(mid + hd) * inv_s));
      float a = (pc - nc + 1e-5f) * rcpf(pc + 1e-5f);
      float alpha = act ? a : 0.0f;
      float q = act ? (1.0f - alpha + 1e-7f) : 1.0f;
      float S = scan_mul_dpp(q);
      float T = carryT * dpp_f<0x138, 0xf>(S, 1.0f);
      float wv = alpha * T;
      float Sw = scan_add_dpp(wv);
      cum1 = carryS + Sw;
      carryS += readlane_f(Sw, 63);
    }

    // padding + normalization folded into the cdf transform
    float wsum = carryS;
    float pad = fmaxf(1e-5f - wsum, 0.0f);
    float wadd = pad / (float)(M - 1);
    float rw = rcpf(wsum + pad);

    // cd[i+1] = min(1, (cumw_i + (i+1)*wadd) * rw)
    cd[lane + 1] = fminf(1.0f, (cum0 + (float)(lane + 1) * wadd) * rw);
    if (has1) {
      int i = lane + 64;
      if (i <= M - 2) cd[i + 1] = fminf(1.0f, (cum1 + (float)(i + 1) * wadd) * rw);
    }
    if (lane == 0) cd[0] = 0.0f;
    wbar();

    // ---- phase B: 17 inverse-CDF samples (lanes 0..16) ----
    if (lane < 17) {
      float u = (float)((double)lane * ((1.0 - 1.0 / 17.0) / 16.0));
      u += (float)(1.0 / 34.0);
      int lo = 0, hi = M;  // searchsorted right on cd[0..M-1]
      while (lo < hi) {
        int md = (lo + hi) >> 1;
        if (cd[md] <= u) lo = md + 1; else hi = md;
      }
      int below = lo - 1;
      if (below < 0) below = 0;
      if (below > M - 1) below = M - 1;
      int above = lo;
      if (above > M - 1) above = M - 1;
      float c0 = cd[below], c1 = cd[above];
      float b0 = sb[below], b1 = sb[above];
      float den = c1 - c0;
      den = (den < 1e-5f) ? 1.0f : den;
      float t = fminf(fmaxf((u - c0) * rcpf(den), 0.0f), 1.0f);
      nb[lane] = b0 + t * (b1 - b0);
    }
    wbar();

    // ---- phase C: stable merge of sorted starts (old first on ties) ----
    const float4 n0 = *(const float4*)(nb + 0);
    const float4 n1 = *(const float4*)(nb + 4);
    const float4 n2 = *(const float4*)(nb + 8);
    const float4 n3 = *(const float4*)(nb + 12);
#pragma unroll
    for (int c = 0; c < 2; ++c) {
      int i = lane + (c << 6);
      if (i <= M - 2) {
        float a = sb[i];
        int cnt = (n0.x < a) + (n0.y < a) + (n0.z < a) + (n0.w < a) +
                  (n1.x < a) + (n1.y < a) + (n1.z < a) + (n1.w < a) +
                  (n2.x < a) + (n2.y < a) + (n2.z < a) + (n2.w < a) +
                  (n3.x < a) + (n3.y < a) + (n3.z < a) + (n3.w < a);
        int pos = i + cnt;
        sb2[pos] = a;
        if (it != 3) sd2[pos] = sd[i];
      }
    }
    if (lane < 16) {
      float b = nb[lane];
      int lo = 0, hi = M - 1;  // upper_bound over old starts sb[0..M-2]
      while (lo < hi) {
        int md = (lo + hi) >> 1;
        if (sb[md] <= b) lo = md + 1; else hi = md;
      }
      int pos = lane + lo;
      sb2[pos] = b;
      if (it != 3) {
        float e = nr + b * fmn;
        float px = ox + dx * e, py = oy + dy * e, pz = oz + dz * e;
        sd2[pos] = sqrtf(px * px + py * py + pz * pz) - 1.0f;
      }
    }
    if (lane == 0) sb2[M + 15] = fmaxf(sb[M - 1], nb[16]);
    wbar();
    {
      float* t = sb; sb = sb2; sb2 = t;
      t = sd; sd = sd2; sd2 = t;
    }
    M += 16;
  }

  // ---- final: out[ray, i, :], i<128; 3x float2 per lane (coalesced) ----
  if (live) {
    float s0 = sb[2 * lane], s1 = sb[2 * lane + 1];
    float e0 = nr + s0 * fmn, e1 = nr + s1 * fmn;
    float ax = ox + dx * e0, ay = oy + dy * e0, az = oz + dz * e0;
    float bx = ox + dx * e1, by = oy + dy * e1, bz = oz + dz * e1;
    float2* o = (float2*)(out + (size_t)ray * 384 + (size_t)lane * 6);
    o[0] = make_float2(ax, ay);
    o[1] = make_float2(az, bx);
    o[2] = make_float2(by, bz);
  }
}

}  // namespace

extern "C" void kernel_launch(void* const* d_in, const int* in_sizes, int n_in,
                              void* d_out, int out_size, void* d_ws, size_t ws_size,
                              hipStream_t stream) {
  const float* org  = (const float*)d_in[0];
  const float* dirp = (const float*)d_in[1];
  const float* nrp  = (const float*)d_in[2];
  const float* frp  = (const float*)d_in[3];
  float* out = (float*)d_out;
  const int R = in_sizes[0] / 3;
  const int grid = (R + RPB - 1) / RPB;
  hipLaunchKernelGGL(neus_sampler, dim3(grid), dim3(RPB * 64), 0, stream,
                     org, dirp, nrp, frp, out, R);
}